// Round 2
// baseline (379.665 us; speedup 1.0000x reference)
//
#include <hip/hip_runtime.h>
#include <hip/hip_bf16.h>
#include <stdint.h>

typedef __bf16 bf16x8 __attribute__((ext_vector_type(8)));
typedef float  f32x4  __attribute__((ext_vector_type(4)));
typedef uint32_t u32x4 __attribute__((ext_vector_type(4)));
typedef unsigned long long u64;

#define M_NODES 100000
#define K_IN    256
#define N_OUT   128
#define N_EDGE  1600000

#define NXCD          8
#define NODES_PER_XCD 12500      // 100000/8 -> 3.2 MB bf16 rows per bucket (< 4 MB L2/XCD)
#define SCATTER_CH    2048       // edges per scatter block

// ---------------------------------------------------------------------------
// Stage 1: h[M,N] = in[M,K] @ w[K,N]. fp32 loads -> bf16 cvt -> MFMA
// 16x16x32 (fp32 accum). Writes fp32 h (nontemporal; never re-read) to d_out
// and a bf16 mirror (cached; stage 2 gathers it) to d_ws.
// v2 (unchanged in R2): wave's full B panel preloaded in 64 VGPRs; grid-stride
// over row tiles; guard-free hot path. Fragment layouts verified previously.
// ---------------------------------------------------------------------------
template <bool FULL>
__device__ __forceinline__ void gemm_tile(
    const float* __restrict__ in, float* __restrict__ h,
    __hip_bfloat16* __restrict__ hmir,
    const bf16x8 (&bfrag)[8][2], const int m0, const int lr, const int q,
    const int nb)
{
    f32x4 acc[4][2];
    #pragma unroll
    for (int mt = 0; mt < 4; ++mt)
        #pragma unroll
        for (int nt = 0; nt < 2; ++nt)
            acc[mt][nt] = f32x4{0.f, 0.f, 0.f, 0.f};

    #pragma unroll
    for (int k8 = 0; k8 < 8; ++k8) {
        const int ka = k8 * 32 + q * 8;
        bf16x8 afrag[4];
        #pragma unroll
        for (int mt = 0; mt < 4; ++mt) {
            const int row = m0 + mt * 16 + lr;
            if (FULL || row < M_NODES) {
                const float* ap = in + (size_t)row * K_IN + ka;
                const f32x4 a0 = *(const f32x4*)ap;
                const f32x4 a1 = *(const f32x4*)(ap + 4);
                #pragma unroll
                for (int j = 0; j < 4; ++j) {
                    afrag[mt][j]     = (__bf16)a0[j];
                    afrag[mt][4 + j] = (__bf16)a1[j];
                }
            } else {
                #pragma unroll
                for (int j = 0; j < 8; ++j) afrag[mt][j] = (__bf16)0.f;
            }
        }
        #pragma unroll
        for (int mt = 0; mt < 4; ++mt)
            #pragma unroll
            for (int nt = 0; nt < 2; ++nt)
                acc[mt][nt] = __builtin_amdgcn_mfma_f32_16x16x32_bf16(
                    afrag[mt], bfrag[k8][nt], acc[mt][nt], 0, 0, 0);
    }

    // C/D: col = lane&15, row = (lane>>4)*4 + reg
    #pragma unroll
    for (int mt = 0; mt < 4; ++mt) {
        const int rb = m0 + mt * 16 + q * 4;
        if (!FULL && rb >= M_NODES) continue;
        #pragma unroll
        for (int nt = 0; nt < 2; ++nt) {
            const int col = nb + nt * 16 + lr;
            #pragma unroll
            for (int r = 0; r < 4; ++r) {
                const float v = acc[mt][nt][r];
                __builtin_nontemporal_store(v, h + (size_t)(rb + r) * N_OUT + col);
                hmir[(size_t)(rb + r) * N_OUT + col] = __float2bfloat16(v);
            }
        }
    }
}

__global__ __launch_bounds__(256) void gemm_h_mfma(
    const float* __restrict__ in,
    const float* __restrict__ w,
    float* __restrict__ h,
    __hip_bfloat16* __restrict__ hmir)
{
    const int lane = threadIdx.x & 63;
    const int wave = threadIdx.x >> 6;
    const int nb   = wave * 32;
    const int lr   = lane & 15;
    const int q    = lane >> 4;

    bf16x8 bfrag[8][2];
    #pragma unroll
    for (int k8 = 0; k8 < 8; ++k8) {
        const int ka = k8 * 32 + q * 8;
        #pragma unroll
        for (int nt = 0; nt < 2; ++nt) {
            const int col = nb + nt * 16 + lr;
            #pragma unroll
            for (int j = 0; j < 8; ++j)
                bfrag[k8][nt][j] = (__bf16)w[(size_t)(ka + j) * N_OUT + col];
        }
    }

    const int ntiles = (M_NODES + 63) / 64;
    const int nfull  = M_NODES / 64;
    for (int t = blockIdx.x; t < ntiles; t += gridDim.x) {
        const int m0 = t * 64;
        if (t < nfull) gemm_tile<true >(in, h, hmir, bfrag, m0, lr, q, nb);
        else           gemm_tile<false>(in, h, hmir, bfrag, m0, lr, q, nb);
    }
}

// int64 edge indices < 1e5: every high word is 0. int32: odd words random.
__device__ inline int detect_i64(const uint32_t* p) {
    return __popcll(__ballot(p[2 * (threadIdx.x & 63) + 1] == 0u)) >= 60;
}

// ---------------------------------------------------------------------------
// R2 prepass: bucket edges by src/12500 into 8 contiguous ranges so the
// compute kernel can pin each bucket's src rows (3.2 MB) in one XCD's L2.
// rec = src | dst<<17 | eid<<34  (17+17+21 = 55 bits).
// ---------------------------------------------------------------------------
__global__ __launch_bounds__(256) void edge_hist(
    const uint32_t* __restrict__ edge_raw, int E, uint32_t* __restrict__ hist)
{
    __shared__ uint32_t lh[NXCD];
    if (threadIdx.x < NXCD) lh[threadIdx.x] = 0;
    const int e64 = detect_i64(edge_raw);
    __syncthreads();
    const int stride = gridDim.x * 256;
    for (int e = blockIdx.x * 256 + threadIdx.x; e < E; e += stride) {
        const int src = e64 ? (int)edge_raw[2 * (size_t)e]
                            : ((const int*)edge_raw)[e];
        atomicAdd(&lh[src / NODES_PER_XCD], 1u);
    }
    __syncthreads();
    if (threadIdx.x < NXCD) atomicAdd(&hist[threadIdx.x], lh[threadIdx.x]);
}

// ctrl layout (uint32): [0:8) hist, [8:16) start, [16:24) cursor
__global__ void bucket_prefix(uint32_t* __restrict__ ctrl)
{
    if (threadIdx.x == 0) {
        uint32_t s = 0;
        for (int b = 0; b < NXCD; ++b) {
            ctrl[8 + b]  = s;
            ctrl[16 + b] = s;
            s += ctrl[b];
        }
    }
}

__global__ __launch_bounds__(256) void edge_scatter(
    const uint32_t* __restrict__ edge_raw, int E,
    uint32_t* __restrict__ cursor,           // ctrl+16
    u64* __restrict__ rec)
{
    const int e64 = detect_i64(edge_raw);
    __shared__ uint32_t cnt[NXCD], base[NXCD], cur[NXCD];
    if (threadIdx.x < NXCD) { cnt[threadIdx.x] = 0; cur[threadIdx.x] = 0; }
    __syncthreads();

    const int e0 = blockIdx.x * SCATTER_CH;
    int src[8], dst[8], bb[8];
    #pragma unroll
    for (int u = 0; u < 8; ++u) {
        const int e = e0 + u * 256 + threadIdx.x;
        if (e < E) {
            if (e64) {
                src[u] = (int)edge_raw[2 * (size_t)e];
                dst[u] = (int)edge_raw[2 * ((size_t)E + e)];
            } else {
                src[u] = ((const int*)edge_raw)[e];
                dst[u] = ((const int*)edge_raw)[(size_t)E + e];
            }
            bb[u] = src[u] / NODES_PER_XCD;
            atomicAdd(&cnt[bb[u]], 1u);
        } else bb[u] = -1;
    }
    __syncthreads();
    if (threadIdx.x < NXCD)
        base[threadIdx.x] = atomicAdd(&cursor[threadIdx.x], cnt[threadIdx.x]);
    __syncthreads();
    #pragma unroll
    for (int u = 0; u < 8; ++u) {
        if (bb[u] >= 0) {
            const int e = e0 + u * 256 + threadIdx.x;
            const uint32_t pos = base[bb[u]] + atomicAdd(&cur[bb[u]], 1u);
            const u64 r = (u64)(uint32_t)src[u] | ((u64)(uint32_t)dst[u] << 17)
                        | ((u64)(uint32_t)e << 34);
            __builtin_nontemporal_store(r, rec + pos);
        }
    }
}

// ---------------------------------------------------------------------------
// R2 compute: block b%8 -> bucket b (XCD round-robin assumption). src gathers
// stay in that XCD's L2 (3.2 MB window, fetched once); dst gathers + streams
// are nontemporal so they don't evict the src window.
// ---------------------------------------------------------------------------
__global__ __launch_bounds__(256) void edge_compute_sorted(
    const __hip_bfloat16* __restrict__ hm,
    const u64* __restrict__ rec,
    const uint32_t* __restrict__ ctrl,       // hist[0:8) start[8:16)
    const float* __restrict__ a,
    float* __restrict__ ew)
{
    const int s   = threadIdx.x & 15;
    const int grp = threadIdx.x >> 4;        // 0..15
    const int b   = blockIdx.x & 7;
    const int j   = blockIdx.x >> 3;
    const uint32_t BPB = gridDim.x >> 3;
    const uint32_t n   = ctrl[b];
    const uint32_t st  = ctrl[8 + b];

    const __bf16* hb = (const __bf16*)hm;
    const f32x4 a0 = *(const f32x4*)(a + s * 8);
    const f32x4 a1 = *(const f32x4*)(a + s * 8 + 4);

    for (uint32_t base = (uint32_t)j * 64 + (uint32_t)grp * 4; base < n;
         base += BPB * 64) {
        const uint32_t rem = n - base;
        const int nv = rem < 4u ? (int)rem : 4;

        u64 r[4];
        #pragma unroll
        for (int u = 0; u < 4; ++u)
            r[u] = (u < nv) ? __builtin_nontemporal_load(rec + st + base + u)
                            : 0ull;

        bf16x8 hs[4], hd[4];
        #pragma unroll
        for (int u = 0; u < 4; ++u) {
            const int src = (int)(r[u] & 0x1FFFF);
            const int dst = (int)((r[u] >> 17) & 0x1FFFF);
            hs[u] = *(const bf16x8*)(hb + (size_t)src * N_OUT + s * 8);
            const u32x4 dv = __builtin_nontemporal_load(
                (const u32x4*)(hb + (size_t)dst * N_OUT + s * 8));
            hd[u] = __builtin_bit_cast(bf16x8, dv);
        }

        #pragma unroll
        for (int u = 0; u < 4; ++u) {
            float sum = 0.f;
            #pragma unroll
            for (int i = 0; i < 4; ++i)
                sum += fabsf((float)hs[u][i] - (float)hd[u][i]) * a0[i];
            #pragma unroll
            for (int i = 0; i < 4; ++i)
                sum += fabsf((float)hs[u][4 + i] - (float)hd[u][4 + i]) * a1[i];
            sum += __shfl_xor(sum, 1, 64);
            sum += __shfl_xor(sum, 2, 64);
            sum += __shfl_xor(sum, 4, 64);
            sum += __shfl_xor(sum, 8, 64);
            if (s == 0 && u < nv)
                __builtin_nontemporal_store(fmaxf(sum, 0.f),
                                            ew + (uint32_t)(r[u] >> 34));
        }
    }
}

// ---------------------------------------------------------------------------
// Fallback (ws too small for rec array): R1's 4-edges-per-group kernel.
// ---------------------------------------------------------------------------
__global__ __launch_bounds__(256) void edge_kernel_bf16(
    const __hip_bfloat16* __restrict__ hm,
    const uint32_t* __restrict__ edge_raw,
    const float* __restrict__ a,
    float* __restrict__ ew,
    int E)
{
    const int e64 = detect_i64(edge_raw);
    const int s  = threadIdx.x & 15;
    const int g  = (int)((blockIdx.x * 256 + threadIdx.x) >> 4);
    const int e0 = g * 4;
    if (e0 >= E) return;

    const __bf16* hb = (const __bf16*)hm;
    const f32x4 a0 = *(const f32x4*)(a + s * 8);
    const f32x4 a1 = *(const f32x4*)(a + s * 8 + 4);

    if (e0 + 3 < E) {
        int srcs[4], dsts[4];
        if (e64) {
            const uint4 s01 = *(const uint4*)(edge_raw + 2 * (size_t)e0);
            const uint4 s23 = *(const uint4*)(edge_raw + 2 * (size_t)e0 + 4);
            const uint4 d01 = *(const uint4*)(edge_raw + 2 * ((size_t)E + e0));
            const uint4 d23 = *(const uint4*)(edge_raw + 2 * ((size_t)E + e0) + 4);
            srcs[0] = (int)s01.x; srcs[1] = (int)s01.z;
            srcs[2] = (int)s23.x; srcs[3] = (int)s23.z;
            dsts[0] = (int)d01.x; dsts[1] = (int)d01.z;
            dsts[2] = (int)d23.x; dsts[3] = (int)d23.z;
        } else {
            const int4 sv = *(const int4*)((const int*)edge_raw + e0);
            const int4 dv = *(const int4*)((const int*)edge_raw + (size_t)E + e0);
            srcs[0] = sv.x; srcs[1] = sv.y; srcs[2] = sv.z; srcs[3] = sv.w;
            dsts[0] = dv.x; dsts[1] = dv.y; dsts[2] = dv.z; dsts[3] = dv.w;
        }

        bf16x8 hs[4], hd[4];
        #pragma unroll
        for (int u = 0; u < 4; ++u) {
            hs[u] = *(const bf16x8*)(hb + (size_t)srcs[u] * N_OUT + s * 8);
            hd[u] = *(const bf16x8*)(hb + (size_t)dsts[u] * N_OUT + s * 8);
        }

        f32x4 rr;
        #pragma unroll
        for (int u = 0; u < 4; ++u) {
            float sum = 0.f;
            #pragma unroll
            for (int i = 0; i < 4; ++i)
                sum += fabsf((float)hs[u][i] - (float)hd[u][i]) * a0[i];
            #pragma unroll
            for (int i = 0; i < 4; ++i)
                sum += fabsf((float)hs[u][4 + i] - (float)hd[u][4 + i]) * a1[i];
            sum += __shfl_xor(sum, 1, 64);
            sum += __shfl_xor(sum, 2, 64);
            sum += __shfl_xor(sum, 4, 64);
            sum += __shfl_xor(sum, 8, 64);
            rr[u] = fmaxf(sum, 0.f);
        }
        if (s == 0) *(f32x4*)(ew + e0) = rr;
    } else {
        for (int e = e0; e < E; ++e) {
            int src, dst;
            if (e64) {
                src = (int)edge_raw[2 * (size_t)e];
                dst = (int)edge_raw[2 * ((size_t)E + e)];
            } else {
                const int* e32 = (const int*)edge_raw;
                src = e32[e];
                dst = e32[(size_t)E + e];
            }
            const bf16x8 hs = *(const bf16x8*)(hb + (size_t)src * N_OUT + s * 8);
            const bf16x8 hd = *(const bf16x8*)(hb + (size_t)dst * N_OUT + s * 8);
            float sum = 0.f;
            #pragma unroll
            for (int i = 0; i < 4; ++i)
                sum += fabsf((float)hs[i] - (float)hd[i]) * a0[i];
            #pragma unroll
            for (int i = 0; i < 4; ++i)
                sum += fabsf((float)hs[4 + i] - (float)hd[4 + i]) * a1[i];
            sum += __shfl_xor(sum, 1, 64);
            sum += __shfl_xor(sum, 2, 64);
            sum += __shfl_xor(sum, 4, 64);
            sum += __shfl_xor(sum, 8, 64);
            if (s == 0) ew[e] = fmaxf(sum, 0.f);
        }
    }
}

__global__ __launch_bounds__(256) void edge_kernel_f32(
    const float* __restrict__ h,
    const uint32_t* __restrict__ edge_raw,
    const float* __restrict__ a,
    float* __restrict__ ew,
    int E)
{
    const int e64 = detect_i64(edge_raw);
    const int s = threadIdx.x & 15;
    const int e = (int)((blockIdx.x * 256 + threadIdx.x) >> 4);
    if (e >= E) return;

    int src, dst;
    if (e64) {
        src = (int)edge_raw[2 * (size_t)e];
        dst = (int)edge_raw[2 * ((size_t)E + e)];
    } else {
        const int* e32 = (const int*)edge_raw;
        src = e32[e];
        dst = e32[(size_t)E + e];
    }

    const f32x4 s0 = *(const f32x4*)(h + (size_t)src * N_OUT + s * 8);
    const f32x4 s1 = *(const f32x4*)(h + (size_t)src * N_OUT + s * 8 + 4);
    const f32x4 d0 = *(const f32x4*)(h + (size_t)dst * N_OUT + s * 8);
    const f32x4 d1 = *(const f32x4*)(h + (size_t)dst * N_OUT + s * 8 + 4);
    const f32x4 a0 = *(const f32x4*)(a + s * 8);
    const f32x4 a1 = *(const f32x4*)(a + s * 8 + 4);

    float sum = 0.f;
    #pragma unroll
    for (int i = 0; i < 4; ++i) sum += fabsf(s0[i] - d0[i]) * a0[i];
    #pragma unroll
    for (int i = 0; i < 4; ++i) sum += fabsf(s1[i] - d1[i]) * a1[i];

    sum += __shfl_xor(sum, 1, 64);
    sum += __shfl_xor(sum, 2, 64);
    sum += __shfl_xor(sum, 4, 64);
    sum += __shfl_xor(sum, 8, 64);

    if (s == 0) ew[e] = fmaxf(sum, 0.f);
}

extern "C" void kernel_launch(void* const* d_in, const int* in_sizes, int n_in,
                              void* d_out, int out_size, void* d_ws, size_t ws_size,
                              hipStream_t stream) {
    const float*    in   = (const float*)d_in[0];
    const uint32_t* edge = (const uint32_t*)d_in[1];
    const float*    w    = (const float*)d_in[2];
    const float*    a    = (const float*)d_in[3];

    float* h  = (float*)d_out;
    float* ew = h + (size_t)M_NODES * N_OUT;

    // ws layout: [mirror 25,600,000][ctrl 1,024][rec 12,800,000]
    const size_t mirror_bytes = (size_t)M_NODES * N_OUT * sizeof(__hip_bfloat16);
    const size_t ctrl_off     = mirror_bytes;            // 256-aligned
    const size_t rec_off      = ctrl_off + 1024;
    const size_t sorted_bytes = rec_off + (size_t)N_EDGE * sizeof(u64);

    __hip_bfloat16* hmir = (ws_size >= mirror_bytes) ? (__hip_bfloat16*)d_ws : nullptr;

    if (hmir && ws_size >= sorted_bytes) {
        uint32_t* ctrl = (uint32_t*)((char*)d_ws + ctrl_off);
        u64*      rec  = (u64*)((char*)d_ws + rec_off);

        hipMemsetAsync(ctrl, 0, 1024, stream);
        edge_hist<<<dim3(512), dim3(256), 0, stream>>>(edge, N_EDGE, ctrl);
        bucket_prefix<<<dim3(1), dim3(64), 0, stream>>>(ctrl);
        edge_scatter<<<dim3((N_EDGE + SCATTER_CH - 1) / SCATTER_CH), dim3(256),
                       0, stream>>>(edge, N_EDGE, ctrl + 16, rec);
        gemm_h_mfma<<<dim3(512), dim3(256), 0, stream>>>(in, w, h, hmir);
        // 25000 blocks: 3125 per bucket; bucket = blockIdx%8 -> XCD round-robin
        edge_compute_sorted<<<dim3(25000), dim3(256), 0, stream>>>(
            hmir, rec, ctrl, a, ew);
    } else if (hmir) {
        gemm_h_mfma<<<dim3(512), dim3(256), 0, stream>>>(in, w, h, hmir);
        const int egroups = (N_EDGE + 3) / 4;
        const int eblocks = (egroups * 16 + 255) / 256;
        edge_kernel_bf16<<<dim3(eblocks), dim3(256), 0, stream>>>(
            hmir, edge, a, ew, N_EDGE);
    } else {
        gemm_h_mfma<<<dim3(512), dim3(256), 0, stream>>>(
            in, w, h, (__hip_bfloat16*)d_ws);
        const int eblocks = (N_EDGE * 16 + 255) / 256;
        edge_kernel_f32<<<dim3(eblocks), dim3(256), 0, stream>>>(
            h, edge, a, ew, N_EDGE);
    }
}